// Round 2
// 196.465 us; speedup vs baseline: 1.0728x; 1.0728x over previous
//
#include <hip/hip_runtime.h>

// CustomRNN: B=2048, T=512, I=1, H=64.
// One wave per batch. R0 was LDS-return-bound: every lane broadcast-read the
// ENTIRE 64-float h (16 ds_read_b128/step). R2: 4-way K-split. Lane
// (q=lane>>4, r=lane&15) reads only its 16-float segment h[16q..16q+16)
// (4 ds_read_b128/step) and accumulates quarter-dots for 4 output rows.
// Cross-lane combine uses __shfl_xor (guaranteed semantics; R1's permlane
// swap guess was wrong). The cndmask selects are folded away by assigning
// accumulators to lane-dependent rows:
//   sA <- row l,    sB <- row l^32,  sC <- row l^16,  sD <- row l^48
// so the butterfly is select-free:
//   u0 = sA + shfl_xor(sB,32)   // row l over segs {q, q^2}
//   u1 = sC + shfl_xor(sD,32)   // row l^16 over segs {q, q^2}
//   a  = u0 + shfl_xor(u1,16)   // row l over all 4 segs -> lands on lane l
// (Hand-checked: lane 5 -> uAB=row5{0,2}, uCD(21)=row5{1,3}, z(5)=a[5].)
// LDS instrs/step/wave: 17 -> 8. Weight cache 64 VGPRs, waves_per_eu(2,2)
// pins the register budget (grid supplies exactly 2 waves/SIMD anyway).

typedef float v2f __attribute__((ext_vector_type(2)));
typedef float v4f __attribute__((ext_vector_type(4)));

#define WPB 4  // waves (== batches) per block

__global__ __launch_bounds__(WPB * 64)
__attribute__((amdgpu_waves_per_eu(2, 2)))
void rnn_fused(
    const float* __restrict__ x,      // [B, T, 1]
    const float* __restrict__ W_ih,   // [64, 1]
    const float* __restrict__ W_hh,   // [64, 64]
    const float* __restrict__ b_ih,   // [64]
    const float* __restrict__ b_hh,   // [64]
    const float* __restrict__ fc_w,   // [1, 64]
    const float* __restrict__ fc_b,   // [1]
    float* __restrict__ out,          // [B, 1]
    int B, int T)
{
    const int lane  = threadIdx.x & 63;
    const int wv    = threadIdx.x >> 6;
    const int batch = blockIdx.x * WPB + wv;
    if (batch >= B) return;  // no block-wide sync anywhere; early exit safe

    const int q = lane >> 4;   // k-segment: k in [16q, 16q+16)

    __shared__ __align__(16) float hs[WPB][64];
    __shared__ __align__(16) float xs[WPB][64];

    // Per-lane row assignment (see header comment): rows for sA..sD.
    const int rA = lane;
    const int rB = lane ^ 32;
    const int rC = lane ^ 16;
    const int rD = lane ^ 48;

    // 4 rows x 16 weights = 64 weights/lane as 32 x v2f (64 VGPRs).
    v2f wA[8], wB[8], wC[8], wD[8];
    {
        const v4f* pA = (const v4f*)(W_hh + rA * 64 + 16 * q);
        const v4f* pB = (const v4f*)(W_hh + rB * 64 + 16 * q);
        const v4f* pC = (const v4f*)(W_hh + rC * 64 + 16 * q);
        const v4f* pD = (const v4f*)(W_hh + rD * 64 + 16 * q);
#pragma unroll
        for (int c = 0; c < 4; ++c) {
            v4f tA = pA[c], tB = pB[c], tC = pC[c], tD = pD[c];
            wA[2*c]   = __builtin_shufflevector(tA, tA, 0, 1);
            wA[2*c+1] = __builtin_shufflevector(tA, tA, 2, 3);
            wB[2*c]   = __builtin_shufflevector(tB, tB, 0, 1);
            wB[2*c+1] = __builtin_shufflevector(tB, tB, 2, 3);
            wC[2*c]   = __builtin_shufflevector(tC, tC, 0, 1);
            wC[2*c+1] = __builtin_shufflevector(tC, tC, 2, 3);
            wD[2*c]   = __builtin_shufflevector(tD, tD, 0, 1);
            wD[2*c+1] = __builtin_shufflevector(tD, tD, 2, 3);
        }
    }
    const float wih_j  = W_ih[lane];            // final a[j] lands on lane j
    const float bias_j = b_ih[lane] + b_hh[lane];

    const float* xb = x + (size_t)batch * T;

    hs[wv][lane] = 0.0f;
    __builtin_amdgcn_wave_barrier();

    float hcur = 0.0f;  // this lane's h[j], mirrored in hs[wv][lane]

    auto step = [&](float xv) {
        // Read only this lane's 16-float segment of h: 4 ds_read_b128.
        // (16-lane groups broadcast; q vs q^2 aliasing is 2-way = free.)
        const v4f* h4 = (const v4f*)(&hs[wv][q * 16]);
        v2f pA = {0.f, 0.f}, pB = {0.f, 0.f}, pC = {0.f, 0.f}, pD = {0.f, 0.f};
#pragma unroll
        for (int c = 0; c < 4; ++c) {
            const v4f hv  = h4[c];
            const v2f hlo = __builtin_shufflevector(hv, hv, 0, 1);
            const v2f hhi = __builtin_shufflevector(hv, hv, 2, 3);
            pA = __builtin_elementwise_fma(hlo, wA[2*c],   pA);
            pB = __builtin_elementwise_fma(hlo, wB[2*c],   pB);
            pC = __builtin_elementwise_fma(hlo, wC[2*c],   pC);
            pD = __builtin_elementwise_fma(hlo, wD[2*c],   pD);
            pA = __builtin_elementwise_fma(hhi, wA[2*c+1], pA);
            pB = __builtin_elementwise_fma(hhi, wB[2*c+1], pB);
            pC = __builtin_elementwise_fma(hhi, wC[2*c+1], pC);
            pD = __builtin_elementwise_fma(hhi, wD[2*c+1], pD);
        }
        const float sA = pA.x + pA.y, sB = pB.x + pB.y;
        const float sC = pC.x + pC.y, sD = pD.x + pD.y;
        // Select-free butterfly reduce-scatter (rows pre-permuted per lane):
        const float u0 = sA + __shfl_xor(sB, 32, 64);
        const float u1 = sC + __shfl_xor(sD, 32, 64);
        const float z  = u0 + __shfl_xor(u1, 16, 64);
        const float a  = z + __builtin_fmaf(xv, wih_j, bias_j);

        // tanh(a) = sign(a) * (1 - e) / (1 + e),  e = exp(-2|a|)
        const float ax = __builtin_fabsf(a);
        const float e  = __builtin_amdgcn_exp2f(ax * -2.885390082f); // exp(-2ax)
        const float rc = __builtin_amdgcn_rcpf(1.0f + e);
        const float th = (1.0f - e) * rc;
        hcur = __builtin_copysignf(th, a);

        __builtin_amdgcn_wave_barrier();   // all reads of this step done
        hs[wv][lane] = hcur;
        __builtin_amdgcn_wave_barrier();   // write ordered before next reads
    };

    for (int t0 = 0; t0 < T; t0 += 64) {
        const int rem = T - t0;
        // Stage up to 64 input scalars for this batch (coalesced 256B load).
        xs[wv][lane] = (lane < rem) ? xb[t0 + lane] : 0.0f;
        __builtin_amdgcn_wave_barrier();

        if (rem >= 64) {
            const v4f* xs4 = (const v4f*)(&xs[wv][0]);
            for (int t4 = 0; t4 < 16; ++t4) {
                const v4f xq = xs4[t4];  // one broadcast b128 per 4 steps
                step(xq.x);
                step(xq.y);
                step(xq.z);
                step(xq.w);
            }
        } else {
            for (int tt = 0; tt < rem; ++tt) step(xs[wv][tt]);
        }
    }

    // fc: out[b] = sum_j h[j] * fc_w[j] + fc_b   (lane j holds h[j])
    float v = hcur * fc_w[lane];
#pragma unroll
    for (int off = 32; off > 0; off >>= 1)
        v += __shfl_xor(v, off, 64);
    if (lane == 0) out[batch] = v + fc_b[0];
}

extern "C" void kernel_launch(void* const* d_in, const int* in_sizes, int n_in,
                              void* d_out, int out_size, void* d_ws, size_t ws_size,
                              hipStream_t stream) {
    const float* x    = (const float*)d_in[0];
    const float* W_ih = (const float*)d_in[1];
    const float* W_hh = (const float*)d_in[2];
    const float* b_ih = (const float*)d_in[3];
    const float* b_hh = (const float*)d_in[4];
    const float* fc_w = (const float*)d_in[5];
    const float* fc_b = (const float*)d_in[6];
    float* out = (float*)d_out;

    const int B = out_size;          // output is [B, 1]
    const int T = in_sizes[0] / B;   // I == 1, so x has B*T elements

    const int blocks = (B + WPB - 1) / WPB;
    rnn_fused<<<blocks, WPB * 64, 0, stream>>>(x, W_ih, W_hh, b_ih, b_hh,
                                               fc_w, fc_b, out, B, T);
}